// Round 7
// baseline (1726.503 us; speedup 1.0000x reference)
//
#include <hip/hip_runtime.h>
#include <hip/hip_bf16.h>

typedef unsigned int u32;
typedef unsigned short u16;
typedef __attribute__((ext_vector_type(8))) short bf16x8;   // 8 bf16 = 4 VGPRs
typedef __attribute__((ext_vector_type(4))) float f32x4;

#define DEVI __device__ __forceinline__

constexpr int AG = 8, H = 100, W = 352, HP = 102, WP = 354;
constexpr int HWp = H * W;          // 35200
constexpr int NB = 2 * WP + 2 * H;  // 908 border pixels per agent

DEVI u16 f2bf(float f) {
  __hip_bfloat16 h = __float2bfloat16(f);
  return *reinterpret_cast<u16*>(&h);
}
DEVI float bf2f(u16 v) { return __uint_as_float(((u32)v) << 16); }

// interleaved channel order within each 32-block: stored 8v+j <-> logical
// {4v+j (j<4), 16+4v+(j-4) (j>=4)} so one 16B unit = one MFMA k-fragment.
DEVI int chperm(int j) { int v = j >> 3, r = j & 7; return (r < 4) ? 4 * v + r : 16 + 4 * v + (r - 4); }
DEVI int chlog(int c) { return (c & ~31) + chperm(c & 31); }

typedef __attribute__((address_space(1))) const u32 as1c_u32;
typedef __attribute__((address_space(3))) u32 as3_u32;
DEVI void gload16(const u16* g, u16* l) {
  __builtin_amdgcn_global_load_lds((as1c_u32*)(const void*)g, (as3_u32*)(void*)l, 16, 0, 0);
}

// ---------------------------------------------------------------------------
// feature slice fp32 NCHW -> padded NHWC(permuted) bf16 interior, via LDS
// transpose. grid: aloc*H*11 blocks; block 256 thr; tile = (a,h) x 32w x 64c.
__global__ void convert_feat(const float* __restrict__ f, u16* __restrict__ dst) {
  __shared__ float t32[64][33];
  int blk = blockIdx.x;
  int wseg = blk % 11;
  int rest = blk / 11;
  int h = rest % H;
  int a = rest / H;
  int t = threadIdx.x;
  int wbase = wseg * 32;
  {
    int w = t & 31;
    int c0 = (t >> 5) * 8;
#pragma unroll
    for (int i = 0; i < 8; ++i) {
      int lc = c0 + i;
      t32[lc][w] = f[((size_t)(a * 64 + lc) * H + h) * W + wbase + w];
    }
  }
  __syncthreads();
  int p = t >> 3;
  int cs = (t & 7) * 8;
  u16 tmp[8];
#pragma unroll
  for (int j = 0; j < 8; ++j) {
    int c = cs + j;
    int lc = (c & 32) + chperm(c & 31);
    tmp[j] = f2bf(t32[lc][p]);
  }
  size_t ob = ((size_t)(a * HP + h + 1) * WP + (wbase + p + 1)) * 64 + cs;
  *reinterpret_cast<uint4*>(dst + ob) = *reinterpret_cast<uint4*>(tmp);
}

// zero the 1-pixel border of a padded NHWC buffer with C channels, nA agents
template <int C>
__global__ void zero_border(u16* __restrict__ buf, int nA) {
  constexpr int CH = C / 8;
  int idx = blockIdx.x * 256 + threadIdx.x;
  int pix = idx / CH;
  int cc = (idx - pix * CH) * 8;
  if (pix >= nA * NB) return;
  int a = pix / NB;
  int b = pix - a * NB;
  int h, w;
  if (b < WP) { h = 0; w = b; }
  else if (b < 2 * WP) { h = HP - 1; w = b - WP; }
  else {
    int bb = b - 2 * WP;
    int bb2 = (bb < H) ? bb : bb - H;
    h = 1 + bb2;
    w = (bb < H) ? 0 : (WP - 1);
  }
  size_t off = ((size_t)(a * HP + h) * WP + w) * C + cc;
  *reinterpret_cast<uint4*>(buf + off) = make_uint4(0u, 0u, 0u, 0u);
}

// w [O][I][kh][kw] fp32 -> rp[s=t*KB+kb][r:O][u:8][jj:8] bf16 with the LDS
// row-XOR swizzle baked in: stored (r,u) holds logical unit lu = u^(r&7).
__global__ void repack_w(const float* __restrict__ w, u16* __restrict__ rp,
                         int O, int I, int taps) {
  int idx = blockIdx.x * 256 + threadIdx.x;
  int total = O * I * taps;
  if (idx >= total) return;
  int jj = idx & 7;
  int u = (idx >> 3) & 7;
  int r = (idx >> 6) % O;
  int s = idx / (O * 64);
  int KB = I >> 6;
  int kb = s % KB;
  int t = s / KB;
  int lu = u ^ (r & 7);
  int g = lu & 3, j32 = lu >> 2;
  int cp = (jj < 4) ? 4 * g + jj : 16 + 4 * g + (jj - 4);
  int i = kb * 64 + j32 * 32 + cp;
  int o = (r & ~31) + chperm(r & 31);
  rp[idx] = f2bf(w[((size_t)o * I + i) * taps + t]);
}

// ---------------------------------------------------------------------------
// Implicit-GEMM conv, BK=64, BN=COUT, double-buffered LDS, 2-phase-per-K-tile
// schedule: ds_read pre-barrier, staging in phase A, one drain per K-tile.
template <int CIN, int BN, int TAPS>
__global__ __launch_bounds__(BN * 2, 2) void conv_k(
    const u16* __restrict__ in, const u16* __restrict__ wrp,
    const float* __restrict__ bias, u16* __restrict__ out,
    int outHp, int outWp, int outPad) {
  constexpr int BM = 128, BK = 64;
  constexpr int KB = CIN / BK;         // 1,2,4
  constexpr int KS = TAPS * KB;
  constexpr int NT = BN * 2;           // threads
  constexpr int WN = BN / 64;          // waves along N
  constexpr int ACH = 1024 / NT;       // A chunks/thread (4 or 2)
  constexpr int BCH = 4;               // B chunks/thread
  constexpr int ASZ = BM * BK;         // elements per A buffer
  constexpr int BSZ = BN * BK;
  __shared__ u16 smem[2 * (ASZ + BSZ)];  // dbuf: A0,A1,B0,B1

  const int tid = threadIdx.x;
  const int lane = tid & 63;
  const int wid = tid >> 6;
  const int wr = wid / WN;             // 0..1
  const int wc = wid % WN;

  // bijective XCD-aware remap (m204)
  int nwg = gridDim.x;
  int orig = blockIdx.x;
  int q = nwg >> 3, r8 = nwg & 7;
  int xcd = orig & 7, pos = orig >> 3;
  int wg = (xcd < r8 ? xcd * (q + 1) : r8 * (q + 1) + (xcd - r8) * q) + pos;
  const int n0 = wg * BM;

  // A staging addresses: chunk c = p*8+u; global supplies lu = u^(p&7)
  int aoff[ACH];
#pragma unroll
  for (int i = 0; i < ACH; ++i) {
    int c = tid + i * NT;
    int p = c >> 3, u = c & 7;
    int lu = u ^ (p & 7);
    int np2 = n0 + p;
    int a = np2 / HWp;
    int r1 = np2 - a * HWp;
    int h = r1 / W;
    int w = r1 - h * W;
    aoff[i] = ((a * HP + h + 1) * WP + (w + 1)) * CIN + lu * 8;
  }

  f32x4 acc[4][4];
#pragma unroll
  for (int m = 0; m < 4; ++m)
#pragma unroll
    for (int n = 0; n < 4; ++n) acc[m][n] = f32x4{0.f, 0.f, 0.f, 0.f};

  const int g = lane >> 4;
  const int arow = lane & 15;
  const int fk = arow & 7;

  // stage all of K-step s into parity s&1 (6 or 8 loads/thread)
  auto stage = [&](int s) {
    int par = s & 1;
    u16* Ad = smem + par * ASZ;
    u16* Bd = smem + 2 * ASZ + par * BSZ;
    int t = (TAPS == 1) ? 0 : s / KB;
    int kb = (TAPS == 1) ? s : s - t * KB;
    int doff = kb * BK + ((TAPS == 9) ? ((t / 3 - 1) * WP + (t % 3 - 1)) * CIN : 0);
    const u16* wtile = wrp + (size_t)s * BSZ;
#pragma unroll
    for (int i = 0; i < ACH; ++i)
      gload16(in + aoff[i] + doff, Ad + (tid + i * NT) * 8);
#pragma unroll
    for (int i = 0; i < BCH; ++i)
      gload16(wtile + (tid + i * NT) * 8, Bd + (tid + i * NT) * 8);
  };

  stage(0);
  asm volatile("s_waitcnt vmcnt(0)" ::: "memory");
  __builtin_amdgcn_s_barrier();        // tile 0 ready for all waves

  for (int s = 0; s < KS; ++s) {
    int par = s & 1;
    const u16* Ab = smem + par * ASZ;
    const u16* Bb = smem + 2 * ASZ + par * BSZ;
    bf16x8 af[4], bfr[4];

    // ---- phase A: j=0 fragment reads, then issue next tile's staging
#pragma unroll
    for (int m = 0; m < 4; ++m)
      af[m] = *reinterpret_cast<const bf16x8*>(
          Ab + (wr * 64 + m * 16 + arow) * 64 + ((g ^ fk) << 3));
#pragma unroll
    for (int n = 0; n < 4; ++n)
      bfr[n] = *reinterpret_cast<const bf16x8*>(
          Bb + (wc * 64 + n * 16 + arow) * 64 + ((g ^ fk) << 3));
    if (s + 1 < KS) stage(s + 1);      // 6-8 loads, ~2 phases of flight
    __builtin_amdgcn_s_barrier();      // opening: reads overlap others' MFMA
    __builtin_amdgcn_s_setprio(1);
#pragma unroll
    for (int m = 0; m < 4; ++m)
#pragma unroll
      for (int n = 0; n < 4; ++n)
        acc[m][n] = __builtin_amdgcn_mfma_f32_16x16x32_bf16(af[m], bfr[n], acc[m][n], 0, 0, 0);
    __builtin_amdgcn_s_setprio(0);
    asm volatile("s_waitcnt lgkmcnt(0)" ::: "memory");
    __builtin_amdgcn_s_barrier();      // closing phase A

    // ---- phase B: j=1
#pragma unroll
    for (int m = 0; m < 4; ++m)
      af[m] = *reinterpret_cast<const bf16x8*>(
          Ab + (wr * 64 + m * 16 + arow) * 64 + (((4 + g) ^ fk) << 3));
#pragma unroll
    for (int n = 0; n < 4; ++n)
      bfr[n] = *reinterpret_cast<const bf16x8*>(
          Bb + (wc * 64 + n * 16 + arow) * 64 + (((4 + g) ^ fk) << 3));
    __builtin_amdgcn_s_barrier();      // opening phase B
    __builtin_amdgcn_s_setprio(1);
#pragma unroll
    for (int m = 0; m < 4; ++m)
#pragma unroll
      for (int n = 0; n < 4; ++n)
        acc[m][n] = __builtin_amdgcn_mfma_f32_16x16x32_bf16(af[m], bfr[n], acc[m][n], 0, 0, 0);
    __builtin_amdgcn_s_setprio(0);
    // drain once per K-tile: own reads done + own next-tile writes landed,
    // then barrier -> next iter's pre-barrier ds_reads are safe for all waves
    asm volatile("s_waitcnt vmcnt(0) lgkmcnt(0)" ::: "memory");
    __builtin_amdgcn_s_barrier();
  }

  // ---- epilogue: bias+relu -> per-wave 4KB LDS tile (2 passes of 32 px)
  __syncthreads();
  float bs[4];
#pragma unroll
  for (int n = 0; n < 4; ++n) bs[n] = bias[chlog(wc * 64 + n * 16 + arow)];
  u16* et = smem + wid * 2048;  // 32 px x 64 ch per wave
#pragma unroll
  for (int pp = 0; pp < 2; ++pp) {
    if (pp) __syncthreads();
#pragma unroll
    for (int mm = 0; mm < 2; ++mm) {
      int m = pp * 2 + mm;
#pragma unroll
      for (int rg = 0; rg < 4; ++rg) {
        int row = mm * 16 + g * 4 + rg;  // 0..31; (row>>2)&3 == g
#pragma unroll
        for (int n = 0; n < 4; ++n) {
          int col = (n * 16 + arow) ^ (g << 4);
          et[row * 64 + col] = f2bf(fmaxf(acc[m][n][rg] + bs[n], 0.f));
        }
      }
    }
    __syncthreads();
#pragma unroll
    for (int jj = 0; jj < 4; ++jj) {
      int p = jj * 8 + (lane >> 3);  // 0..31
      int un = lane & 7;
      int su = un ^ (((p >> 2) & 3) << 1);
      uint4 qv = *reinterpret_cast<const uint4*>(et + p * 64 + su * 8);
      int np2 = n0 + wr * 64 + pp * 32 + p;
      int a = np2 / HWp;
      int r1 = np2 - a * HWp;
      int h = r1 / W;
      int w = r1 - h * W;
      size_t ob = ((size_t)(a * outHp + h + outPad) * outWp + (w + outPad)) * BN +
                  wc * 64 + un * 8;
      *reinterpret_cast<uint4*>(out + ob) = qv;
    }
  }
}

// ---------------------------------------------------------------------------
// box-mean pooling over y slice [nA][100][352][256] bf16(permuted) -> desc fp32
__global__ void pool_k(const u16* __restrict__ y, const int* __restrict__ boxes,
                       float* __restrict__ desc) {
  int blk = blockIdx.x;  // local: a*50 + k
  const int* bx = boxes + blk * 4;
  int a = blk / 50;
  int l = bx[0], r = bx[1], u = bx[2], d = bx[3];
  int c = threadIdx.x;
  float s = 0.f;
  for (int h = u; h < d; ++h) {
    const u16* row = y + ((size_t)(a * H + h) * W) * 256 + c;
    for (int w2 = l; w2 < r; ++w2) s += bf2f(row[(size_t)w2 * 256]);
  }
  desc[(size_t)blk * 256 + chlog(c)] = s / (float)((d - u) * (r - l));
}

// ---------------------------------------------------------------------------
extern "C" void kernel_launch(void* const* d_in, const int* in_sizes, int n_in,
                              void* d_out, int out_size, void* d_ws, size_t ws_size,
                              hipStream_t stream) {
  const float* feature = (const float*)d_in[0];
  const int* boxes = (const int*)d_in[1];
  const float* w1a = (const float*)d_in[2];
  const float* b1a = (const float*)d_in[3];
  const float* w1b = (const float*)d_in[4];
  const float* b1b = (const float*)d_in[5];
  const float* w2a = (const float*)d_in[6];
  const float* b2a = (const float*)d_in[7];
  const float* w2b = (const float*)d_in[8];
  const float* b2b = (const float*)d_in[9];
  const float* w3a = (const float*)d_in[10];
  const float* b3a = (const float*)d_in[11];
  const float* w3b = (const float*)d_in[12];
  const float* b3b = (const float*)d_in[13];
  const float* wDa = (const float*)d_in[14];
  const float* bDa = (const float*)d_in[15];
  const float* wDb = (const float*)d_in[16];
  const float* bDb = (const float*)d_in[17];
  const float* wF = (const float*)d_in[18];
  const float* bF = (const float*)d_in[19];

  const size_t WB = (size_t)2 * ((size_t)9 * 64 * 128 + 3 * 9 * 128 * 128 +
                                 (size_t)9 * 128 * 256 + 2 * 9 * 256 * 256 +
                                 2 * 256 * 256);  // repacked weight bytes
  // per-agent activation bytes: (128+128+256+256+64) ch * HP*WP * 2B
  const size_t PER_A = (size_t)832 * HP * WP * 2;
  int aloc = (ws_size >= 4 * PER_A + WB) ? 4 : 2;  // agents per slice
  const int npixl = aloc * HWp;

  char* ws = (char*)d_ws;
  const size_t SZ128 = (size_t)aloc * HP * WP * 128 * 2;
  const size_t SZ256 = (size_t)aloc * HP * WP * 256 * 2;
  const size_t SZ64  = (size_t)aloc * HP * WP * 64 * 2;
  u16* X  = (u16*)(ws);
  u16* Y  = (u16*)(ws + SZ128);
  u16* S0 = (u16*)(ws + 2 * SZ128);
  u16* S1 = (u16*)(ws + 2 * SZ128 + SZ256);
  u16* in64 = (u16*)(ws + 2 * SZ128 + 2 * SZ256);
  u16* rp = (u16*)(ws + 2 * SZ128 + 2 * SZ256 + SZ64);

  const size_t o1a = 0;
  const size_t o1b = o1a + (size_t)9 * 64 * 128;
  const size_t o2a = o1b + (size_t)9 * 128 * 128;
  const size_t o2b = o2a + (size_t)9 * 128 * 128;
  const size_t o3a = o2b + (size_t)9 * 128 * 128;
  const size_t o3b = o3a + (size_t)9 * 128 * 256;
  const size_t oDa = o3b + (size_t)9 * 256 * 256;
  const size_t oDb = oDa + (size_t)9 * 256 * 256;
  const size_t oF = oDb + (size_t)256 * 256;

  auto rpk = [&](const float* wsrc, size_t off, int O, int I, int taps) {
    int total = O * I * taps;
    repack_w<<<(total + 255) / 256, 256, 0, stream>>>(wsrc, rp + off, O, I, taps);
  };
  rpk(w1a, o1a, 128, 64, 9);
  rpk(w1b, o1b, 128, 128, 9);
  rpk(w2a, o2a, 128, 128, 9);
  rpk(w2b, o2b, 128, 128, 9);
  rpk(w3a, o3a, 256, 128, 9);
  rpk(w3b, o3b, 256, 256, 9);
  rpk(wDa, oDa, 256, 256, 9);
  rpk(wDb, oDb, 256, 256, 1);
  rpk(wF, oF, 256, 256, 1);

  // borders never corrupted: zero once per call
  zero_border<64><<<(aloc * NB * 8 + 255) / 256, 256, 0, stream>>>(in64, aloc);
  zero_border<128><<<(aloc * NB * 16 + 255) / 256, 256, 0, stream>>>(X, aloc);
  zero_border<128><<<(aloc * NB * 16 + 255) / 256, 256, 0, stream>>>(Y, aloc);
  zero_border<256><<<(aloc * NB * 32 + 255) / 256, 256, 0, stream>>>(S1, aloc);

  const int G = npixl / 128;  // 550 or 1100
  for (int a0 = 0; a0 < AG; a0 += aloc) {
    // S0's padded border was overwritten by previous slice's unpadded convF
    zero_border<256><<<(aloc * NB * 32 + 255) / 256, 256, 0, stream>>>(S0, aloc);

    convert_feat<<<aloc * H * 11, 256, 0, stream>>>(
        feature + (size_t)a0 * 64 * H * W, in64);

    conv_k<64, 128, 9><<<G, 256, 0, stream>>>(in64, rp + o1a, b1a, X, HP, WP, 1);
    conv_k<128, 128, 9><<<G, 256, 0, stream>>>(X, rp + o1b, b1b, Y, HP, WP, 1);
    conv_k<128, 128, 9><<<G, 256, 0, stream>>>(Y, rp + o2a, b2a, X, HP, WP, 1);
    conv_k<128, 128, 9><<<G, 256, 0, stream>>>(X, rp + o2b, b2b, Y, HP, WP, 1);
    conv_k<128, 256, 9><<<G, 512, 0, stream>>>(Y, rp + o3a, b3a, S0, HP, WP, 1);
    conv_k<256, 256, 9><<<G, 512, 0, stream>>>(S0, rp + o3b, b3b, S1, HP, WP, 1);
    conv_k<256, 256, 9><<<G, 512, 0, stream>>>(S1, rp + oDa, bDa, S0, HP, WP, 1);
    conv_k<256, 256, 1><<<G, 512, 0, stream>>>(S0, rp + oDb, bDb, S1, HP, WP, 1);
    conv_k<256, 256, 1><<<G, 512, 0, stream>>>(S1, rp + oF, bF, S0, H, W, 0);

    pool_k<<<aloc * 50, 256, 0, stream>>>(S0, boxes + (size_t)a0 * 50 * 4,
                                          ((float*)d_out) + (size_t)a0 * 50 * 256);
  }
}